// Round 1
// 287.175 us; speedup vs baseline: 1.0301x; 1.0301x over previous
//
#include <hip/hip_runtime.h>

// PPNM layer: out = m + b_s[:,None] * m*m, m = x @ W
//   x: [B, 16] fp32, W: [16, 224] fp32, b_s: [B] fp32, out: [B, 224] fp32
//
// Memory-bound: 235 MB write + ~18 MB read => ~40 us floor at 6.3 TB/s.
//
// R2 changes vs R1 (R1 kernel-proper ~150 us, latency-bound):
//  - Depth-2 software pipeline (two independent prefetch stages, manual
//    unroll-by-2 so all stage registers are statically indexed).
//    R1 waited on loads issued only ONE iteration earlier (~250-cycle
//    window vs ~600-900-cycle L3/HBM load latency) -> per-iteration
//    stall, ~1 outstanding store per wave (loads+stores share vmcnt).
//    Depth 2 doubles the latency window and keeps the previous store
//    in flight across the counted wait.
//  - Same geometry: 448 threads = 7 full waves, each wave stores 1024
//    contiguous bytes; __launch_bounds__(448,4) caps VGPR at 128 ->
//    2 blocks/CU (14 waves). Stage regs: 64 (Wf) + 2x17 + temps ~ 116.

#define LBANDS 224
#define EMEMB  16
#define GROUPS 56                  // LBANDS / 4
#define PROWS  8                   // pixel rows per block tile
#define NTHREADS (GROUPS * PROWS)  // 448 = 7 full waves

__global__ __launch_bounds__(NTHREADS, 4) void ppnm_kernel(
    const float* __restrict__ x,    // [B, 16]
    const float* __restrict__ w,    // [16, 224]
    const float* __restrict__ bs,   // [B]
    float* __restrict__ out,        // [B, 224]
    int B)
{
    const int t  = threadIdx.x;
    const int g  = t % GROUPS;   // band group: bands [4g, 4g+4)
    const int pr = t / GROUPS;   // pixel row within tile: 0..7

    // W fragment for this thread's band group: Wf[k] = w[k][4g..4g+3].
    // 64 VGPRs; loaded once from L2, amortized over the grid-stride loop.
    float4 Wf[EMEMB];
    #pragma unroll
    for (int k = 0; k < EMEMB; ++k) {
        Wf[k] = *reinterpret_cast<const float4*>(w + k * LBANDS + 4 * g);
    }

    const int tiles  = B / PROWS;   // 32768 for B=262144
    const int stride = gridDim.x;

    int tile = blockIdx.x;
    if (tile >= tiles) return;

    // ---- software pipeline, depth 2: stage0 = tile, stage1 = tile+stride ----
    float4 a0, b0, c0, d0; float s0;
    float4 a1, b1, c1, d1; float s1;

    {
        const int p = tile * PROWS + pr;
        const float4* xr = reinterpret_cast<const float4*>(x + p * EMEMB);
        a0 = xr[0]; b0 = xr[1]; c0 = xr[2]; d0 = xr[3];
        s0 = bs[p];
    }
    {
        const int t1 = tile + stride;
        if (t1 < tiles) {
            const int p = t1 * PROWS + pr;
            const float4* xr = reinterpret_cast<const float4*>(x + p * EMEMB);
            a1 = xr[0]; b1 = xr[1]; c1 = xr[2]; d1 = xr[3];
            s1 = bs[p];
        }
    }

    // m = x_row . W[:, 4g:4g+4] (64 FMAs, ILP=4); out = m + b*m*m.
#define PPNM_BODY(AA, BB, CC, DD, SS, TT) do {                                \
        const float xs_[EMEMB] = { AA.x, AA.y, AA.z, AA.w,                    \
                                   BB.x, BB.y, BB.z, BB.w,                    \
                                   CC.x, CC.y, CC.z, CC.w,                    \
                                   DD.x, DD.y, DD.z, DD.w };                  \
        float4 acc = make_float4(0.f, 0.f, 0.f, 0.f);                         \
        _Pragma("unroll")                                                     \
        for (int k = 0; k < EMEMB; ++k) {                                     \
            acc.x = fmaf(xs_[k], Wf[k].x, acc.x);                             \
            acc.y = fmaf(xs_[k], Wf[k].y, acc.y);                             \
            acc.z = fmaf(xs_[k], Wf[k].z, acc.z);                             \
            acc.w = fmaf(xs_[k], Wf[k].w, acc.w);                             \
        }                                                                     \
        float4 r;                                                             \
        r.x = fmaf((SS) * acc.x, acc.x, acc.x);                               \
        r.y = fmaf((SS) * acc.y, acc.y, acc.y);                               \
        r.z = fmaf((SS) * acc.z, acc.z, acc.z);                               \
        r.w = fmaf((SS) * acc.w, acc.w, acc.w);                               \
        *reinterpret_cast<float4*>(out + ((TT) * PROWS + pr) * LBANDS + 4 * g) = r; \
    } while (0)

#define PPNM_PREFETCH(AA, BB, CC, DD, SS, TT) do {                            \
        const int p_ = (TT) * PROWS + pr;                                     \
        const float4* xr_ = reinterpret_cast<const float4*>(x + p_ * EMEMB);  \
        AA = xr_[0]; BB = xr_[1]; CC = xr_[2]; DD = xr_[3];                   \
        SS = bs[p_];                                                          \
    } while (0)

    for (;;) {
        // consume stage0 (current tile), then refill it for tile + 2*stride
        PPNM_BODY(a0, b0, c0, d0, s0, tile);
        {
            const int tn = tile + 2 * stride;
            if (tn < tiles) PPNM_PREFETCH(a0, b0, c0, d0, s0, tn);
        }
        tile += stride;
        if (tile >= tiles) break;

        // consume stage1, refill for tile + 2*stride
        PPNM_BODY(a1, b1, c1, d1, s1, tile);
        {
            const int tn = tile + 2 * stride;
            if (tn < tiles) PPNM_PREFETCH(a1, b1, c1, d1, s1, tn);
        }
        tile += stride;
        if (tile >= tiles) break;
    }

#undef PPNM_BODY
#undef PPNM_PREFETCH
}

extern "C" void kernel_launch(void* const* d_in, const int* in_sizes, int n_in,
                              void* d_out, int out_size, void* d_ws, size_t ws_size,
                              hipStream_t stream) {
    const float* x  = (const float*)d_in[0];   // [B, 16]
    const float* w  = (const float*)d_in[1];   // [16, 224]
    const float* bs = (const float*)d_in[2];   // [B]
    float* out = (float*)d_out;

    const int B = in_sizes[2];                 // 262144

    // 2048 blocks: 16 tiles each amortize the per-thread W-fragment load;
    // ~2 resident blocks/CU (14 waves) under the 128-VGPR cap.
    const int grid = 2048;
    ppnm_kernel<<<grid, NTHREADS, 0, stream>>>(x, w, bs, out, B);
}